// Round 3
// baseline (19005.034 us; speedup 1.0000x reference)
//
#include <hip/hip_runtime.h>
#include <math.h>

#define TT 2048
#define NG 64

// ---- workspace layout (bytes); total 933,888 (assumes ws_size >= ~1MB) ----
// flags: fA/fB/fC = int[NG] strided 64B each
#define FA_OFF   0
#define FB_OFF   4096
#define FC_OFF   8192
#define STRM_OFF 16384                 // A streamed weights: half[8c][4hs][512id][8] = 262144
#define H1_OFF   278528                // u16 [8 slot][64 g][2 b][256]  = 524288
#define H2_OFF   802816                // u16 [4 slot][64 g][2 b][128]  = 131072

typedef _Float16 half2v __attribute__((ext_vector_type(2)));
typedef _Float16 half8v __attribute__((ext_vector_type(8)));
typedef unsigned long long u64;

#if defined(__has_builtin)
#if __has_builtin(__builtin_amdgcn_fdot2)
#define HAVE_FDOT2 1
#endif
#endif

__device__ __forceinline__ float fdot2f(half2v a, half2v b, float c) {
#ifdef HAVE_FDOT2
    return __builtin_amdgcn_fdot2(a, b, c, false);
#else
    return c + (float)a.x * (float)b.x + (float)a.y * (float)b.y;
#endif
}
__device__ __forceinline__ half2v h2at(half8v v, int m) {
    half2v r; r.x = v[2 * m]; r.y = v[2 * m + 1]; return r;
}
__device__ __forceinline__ float sigf(float x) { return 1.0f / (1.0f + __expf(-x)); }
__device__ __forceinline__ float tanh_f(float x) {
    float t = __expf(fminf(2.0f * x, 30.0f));
    return (t - 1.0f) / (t + 1.0f);
}
template<int CTRL, int XM>
__device__ __forceinline__ float xadd(float v) {
#if __has_builtin(__builtin_amdgcn_mov_dpp)
    int t = __builtin_amdgcn_mov_dpp(__builtin_bit_cast(int, v), CTRL, 0xF, 0xF, true);
    return v + __builtin_bit_cast(float, t);
#else
    return v + __shfl_xor(v, XM, 64);
#endif
}
__device__ __forceinline__ float xadd4(float v) {
#if __has_builtin(__builtin_amdgcn_ds_swizzle)
    int t = __builtin_amdgcn_ds_swizzle(__builtin_bit_cast(int, v), 0x101F);
    return v + __builtin_bit_cast(float, t);
#else
    return v + __shfl_xor(v, 4, 64);
#endif
}
__device__ __forceinline__ float bf8f(float a){ a=xadd<0xB1,1>(a); a=xadd<0x4E,2>(a); return xadd4(a); }
__device__ __forceinline__ float bf4f(float a){ a=xadd<0xB1,1>(a); return xadd<0x4E,2>(a); }
__device__ __forceinline__ float bf2f(float a){ return xadd<0xB1,1>(a); }

__device__ __forceinline__ _Float16 lstm_fin(float g0,float g1,float g2,float g3,float& c){
    float ig=sigf(g0), fg=sigf(g1), gg=tanh_f(g2), og=sigf(g3);
    float cn = fmaf(fg, c, ig*gg); c = cn;
    return (_Float16)(og * tanh_f(cn));
}
__device__ __forceinline__ int aload(const int* p) {
    return __hip_atomic_load((int*)p, __ATOMIC_RELAXED, __HIP_MEMORY_SCOPE_AGENT);
}
__device__ __forceinline__ int spin_ge(const int* p, int tgt) {
    int v = aload(p);
    while (v < tgt) { __builtin_amdgcn_s_sleep(1); v = aload(p); }
    return v;
}
__device__ __forceinline__ void apost(int* p, int v) {
    __hip_atomic_store(p, v, __ATOMIC_RELAXED, __HIP_MEMORY_SCOPE_AGENT);
}
__device__ __forceinline__ u64 aload64(const u64* p) {
    return __hip_atomic_load((u64*)p, __ATOMIC_RELAXED, __HIP_MEMORY_SCOPE_AGENT);
}
__device__ __forceinline__ void astore64(u64* p, u64 v) {
    __hip_atomic_store(p, v, __ATOMIC_RELAXED, __HIP_MEMORY_SCOPE_AGENT);
}

// ---- prep: zero flags + pack A's streamed half of W1hh (u=2,3) as fp16 ----
__global__ __launch_bounds__(512)
void prep_v4(char* ws, const float* w1hh) {
    int t = blockIdx.x * 512 + threadIdx.x;
    if (t < 3072) ((int*)ws)[t] = 0;
    _Float16* strm = (_Float16*)(ws + STRM_OFF);
    for (int i = t; i < 131072; i += gridDim.x * 512) {
        int e = i & 7;
        int rest = i >> 3;
        int id = rest & 511; rest >>= 9;      // rest = c*4+hs
        int hs = rest & 3, c = rest >> 2;     // c = jj*2+cc
        int jj = c >> 1, cc = c & 1;
        int row = hs * 256 + ((id >> 3) << 2) + 2 + cc;   // gate hs, unit rg*4+(2+cc)
        int col = (id & 7) * 32 + jj * 8 + e;             // kg*32 + jj*8 + e
        strm[i] = (_Float16)w1hh[row * 256 + col];
    }
}

__global__ __launch_bounds__(512, 2)
void lstm_v4(const float* __restrict__ inp,
             const float* __restrict__ w1ih, const float* __restrict__ w1hh,
             const float* __restrict__ b1ih, const float* __restrict__ b1hh,
             const float* __restrict__ w2ih, const float* __restrict__ w2hh,
             const float* __restrict__ b2ih, const float* __restrict__ b2hh,
             const float* __restrict__ w3ih, const float* __restrict__ w3hh,
             const float* __restrict__ b3ih, const float* __restrict__ b3hh,
             const float* __restrict__ w4ih, const float* __restrict__ w4hh,
             const float* __restrict__ b4ih, const float* __restrict__ b4hh,
             const float* __restrict__ w5ih, const float* __restrict__ w5hh,
             const float* __restrict__ b5ih, const float* __restrict__ b5hh,
             const float* __restrict__ wlin, const float* __restrict__ blin,
             float* __restrict__ out, char* __restrict__ wsb)
{
    __shared__ __align__(16) char smem[12800];

    const int tid  = threadIdx.x;
    const int lane = tid & 63;
    const int wave = tid >> 6;
    const int g  = blockIdx.x / 3;     // group: batches g*2, g*2+1
    const int st = blockIdx.x % 3;     // 0=A(L1) 1=B(L2) 2=C(L3..5+head)

    int* fAp = (int*)(wsb + FA_OFF) + g * 16;
    int* fBp = (int*)(wsb + FB_OFF) + g * 16;
    int* fCp = (int*)(wsb + FC_OFF) + g * 16;

    // =================================================================== A
    if (st == 0) {
        _Float16* XA   = (_Float16*)smem;            // [2][2][8kg][40]  (pad: conflict-free + 16B align)
        _Float16* funA = (_Float16*)(smem + 2560);   // [2][2][256] compact for funnel
        float* biasA   = (float*)(smem + 4608);      // [256][4]
        float* w1xA    = (float*)(smem + 8704);      // [256][4]
        const _Float16* strm = (const _Float16*)(wsb + STRM_OFF);

        const int kg = tid & 7, rg = tid >> 3;       // KG=8, 64 rg-slots, 4 units/slot

        // resident weights: units u=0,1 (u2,u3 streamed per step)
        half8v wA[2][4][4];
#pragma unroll
        for (int uu = 0; uu < 2; ++uu)
#pragma unroll
            for (int gg = 0; gg < 4; ++gg) {
                const int row = gg * 256 + rg * 4 + uu;
#pragma unroll
                for (int jj = 0; jj < 4; ++jj) {
                    half8v w;
#pragma unroll
                    for (int e = 0; e < 8; ++e)
                        w[e] = (_Float16)w1hh[row * 256 + kg * 32 + jj * 8 + e];
                    wA[uu][gg][jj] = w;
                }
            }
        for (int i = tid; i < 1024; i += 512) {
            int unit = i >> 2, gg = i & 3;
            biasA[i] = b1ih[gg * 256 + unit] + b1hh[gg * 256 + unit];
            w1xA[i]  = w1ih[gg * 256 + unit];
        }
        for (int i = tid; i < 640; i += 512) XA[i] = (_Float16)0.f;  // x(0) = h1(-1) = 0
        __syncthreads();

        float cA[2] = {0.f, 0.f};
        half8v buf[4][4];

        for (int s = 0; s <= 2048; ++s) {
            const int ps = s & 1;

            // wave0: funnel h1(s-1) -> board (fire-and-forget; drained at tail)
            if (wave == 0 && s >= 1) {
                const u64* fsrc = (const u64*)(funA + ((s - 1) & 1) * 512);
                u64 v0 = fsrc[lane * 2], v1 = fsrc[lane * 2 + 1];
                u64* dst = (u64*)(wsb + H1_OFF + (size_t)((((s - 1) & 7) * NG) + g) * 1024);
                astore64(dst + lane * 2,     v0);
                astore64(dst + lane * 2 + 1, v1);
            }

            if (s < 2048) {
                // issue streamed chunks 0..3 + x_t early
#pragma unroll
                for (int c = 0; c < 4; ++c)
#pragma unroll
                    for (int hs = 0; hs < 4; ++hs)
                        buf[c][hs] = *(const half8v*)(strm + (((c * 4 + hs) * 512 + tid) << 3));
                float xt0 = inp[(size_t)(g * 2) * TT + s];
                float xt1 = inp[(size_t)(g * 2 + 1) * TT + s];

                float aA[2][4][2];
#pragma unroll
                for (int uu = 0; uu < 2; ++uu)
#pragma unroll
                    for (int gg = 0; gg < 4; ++gg) { aA[uu][gg][0] = 0.f; aA[uu][gg][1] = 0.f; }

                // ---- round 0: resident units 0,1 ----
#pragma unroll
                for (int jj = 0; jj < 4; ++jj) {
                    half8v xv0 = *(const half8v*)(XA + ps * 640 + 0 * 320 + kg * 40 + jj * 8);
                    half8v xv1 = *(const half8v*)(XA + ps * 640 + 1 * 320 + kg * 40 + jj * 8);
#pragma unroll
                    for (int uu = 0; uu < 2; ++uu)
#pragma unroll
                        for (int gg = 0; gg < 4; ++gg)
#pragma unroll
                            for (int mm = 0; mm < 4; ++mm) {
                                aA[uu][gg][0] = fdot2f(h2at(wA[uu][gg][jj], mm), h2at(xv0, mm), aA[uu][gg][0]);
                                aA[uu][gg][1] = fdot2f(h2at(wA[uu][gg][jj], mm), h2at(xv1, mm), aA[uu][gg][1]);
                            }
                }
#pragma unroll
                for (int uu = 0; uu < 2; ++uu)
#pragma unroll
                    for (int gg = 0; gg < 4; ++gg) {
                        aA[uu][gg][0] = bf8f(aA[uu][gg][0]);
                        aA[uu][gg][1] = bf8f(aA[uu][gg][1]);
                    }
                if (kg < 4) {
                    const int uu = kg & 1, b = kg >> 1;
                    const int unit = rg * 4 + uu;
                    const float4 bb = *(const float4*)&biasA[unit * 4];
                    const float4 wx = *(const float4*)&w1xA[unit * 4];
                    const float xb = b ? xt1 : xt0;
                    _Float16 hf = lstm_fin(fmaf(wx.x, xb, aA[uu][0][b] + bb.x),
                                           fmaf(wx.y, xb, aA[uu][1][b] + bb.y),
                                           fmaf(wx.z, xb, aA[uu][2][b] + bb.z),
                                           fmaf(wx.w, xb, aA[uu][3][b] + bb.w), cA[0]);
                    XA[((s + 1) & 1) * 640 + b * 320 + (unit >> 5) * 40 + (unit & 31)] = hf;
                    funA[(s & 1) * 512 + b * 256 + unit] = hf;
                }

                // ---- round 1: streamed units 2,3 ----
#pragma unroll
                for (int uu = 0; uu < 2; ++uu)
#pragma unroll
                    for (int gg = 0; gg < 4; ++gg) { aA[uu][gg][0] = 0.f; aA[uu][gg][1] = 0.f; }
#pragma unroll
                for (int jj = 0; jj < 4; ++jj) {
                    half8v xv0 = *(const half8v*)(XA + ps * 640 + 0 * 320 + kg * 40 + jj * 8);
                    half8v xv1 = *(const half8v*)(XA + ps * 640 + 1 * 320 + kg * 40 + jj * 8);
                    const int s0 = (jj * 2) & 3, s1 = (jj * 2 + 1) & 3;
#pragma unroll
                    for (int gg = 0; gg < 4; ++gg)
#pragma unroll
                        for (int mm = 0; mm < 4; ++mm) {
                            aA[0][gg][0] = fdot2f(h2at(buf[s0][gg], mm), h2at(xv0, mm), aA[0][gg][0]);
                            aA[0][gg][1] = fdot2f(h2at(buf[s0][gg], mm), h2at(xv1, mm), aA[0][gg][1]);
                            aA[1][gg][0] = fdot2f(h2at(buf[s1][gg], mm), h2at(xv0, mm), aA[1][gg][0]);
                            aA[1][gg][1] = fdot2f(h2at(buf[s1][gg], mm), h2at(xv1, mm), aA[1][gg][1]);
                        }
                    if (jj < 2) {   // refill consumed slots with chunks 4+2jj, 5+2jj
#pragma unroll
                        for (int hs = 0; hs < 4; ++hs) {
                            buf[s0][hs] = *(const half8v*)(strm + ((((4 + jj * 2) * 4 + hs) * 512 + tid) << 3));
                            buf[s1][hs] = *(const half8v*)(strm + ((((5 + jj * 2) * 4 + hs) * 512 + tid) << 3));
                        }
                    }
                }
#pragma unroll
                for (int uu = 0; uu < 2; ++uu)
#pragma unroll
                    for (int gg = 0; gg < 4; ++gg) {
                        aA[uu][gg][0] = bf8f(aA[uu][gg][0]);
                        aA[uu][gg][1] = bf8f(aA[uu][gg][1]);
                    }
                if (kg < 4) {
                    const int uu = kg & 1, b = kg >> 1;
                    const int unit = rg * 4 + 2 + uu;
                    const float4 bb = *(const float4*)&biasA[unit * 4];
                    const float4 wx = *(const float4*)&w1xA[unit * 4];
                    const float xb = b ? xt1 : xt0;
                    _Float16 hf = lstm_fin(fmaf(wx.x, xb, aA[uu][0][b] + bb.x),
                                           fmaf(wx.y, xb, aA[uu][1][b] + bb.y),
                                           fmaf(wx.z, xb, aA[uu][2][b] + bb.z),
                                           fmaf(wx.w, xb, aA[uu][3][b] + bb.w), cA[1]);
                    XA[((s + 1) & 1) * 640 + b * 320 + (unit >> 5) * 40 + (unit & 31)] = hf;
                    funA[(s & 1) * 512 + b * 256 + unit] = hf;
                }
            }

            // tail: wave0 drains (cheap by now), posts fA=s (h1(s-1) visible), WAR vs B
            if (wave == 0) {
                asm volatile("s_waitcnt vmcnt(0)" ::: "memory");
                if (lane == 0 && s >= 1) apost(fAp, s);
                if (lane == 0 && s >= 9) spin_ge(fBp, s - 8);
            }
            __syncthreads();
        }
        return;
    }

    // =================================================================== B
    if (st == 1) {
        _Float16* XB   = (_Float16*)smem;            // [2][2][8kg][56] (x = h1|h2, padded)
        _Float16* funB = (_Float16*)(smem + 3584);   // [2][2][128]
        float* biasB   = (float*)(smem + 4608);      // [128][4]

        const int kg = tid & 7, rg = tid >> 3;       // KG=8, 64 rg, 2 units/lane

        half8v wB[2][4][6];
#pragma unroll
        for (int uu = 0; uu < 2; ++uu)
#pragma unroll
            for (int gg = 0; gg < 4; ++gg) {
                const int row = gg * 128 + rg * 2 + uu;
#pragma unroll
                for (int jj = 0; jj < 6; ++jj) {
                    half8v w;
#pragma unroll
                    for (int e = 0; e < 8; ++e) {
                        const int k = kg * 48 + jj * 8 + e;
                        float v = (k < 256) ? w2ih[row * 256 + k] : w2hh[row * 128 + (k - 256)];
                        w[e] = (_Float16)v;
                    }
                    wB[uu][gg][jj] = w;
                }
            }
        for (int i = tid; i < 512; i += 512) {
            int unit = i >> 2, gg = i & 3;
            biasB[i] = b2ih[gg * 128 + unit] + b2hh[gg * 128 + unit];
        }
        for (int i = tid; i < 896; i += 512) XB[i] = (_Float16)0.f;   // x(0): h2(-1)=0
        __syncthreads();
        // prologue: stage h1(0)
        spin_ge(fAp, 1);
        if (lane < 16) {
            u64 pf = aload64((const u64*)(wsb + H1_OFF + (size_t)g * 1024) + (wave * 16 + lane));
            int hh = (wave * 16 + lane) * 4, b = hh >> 8, off = hh & 255;
            *(u64*)(XB + b * 448 + (off / 48) * 56 + (off % 48)) = pf;
        }
        __syncthreads();

        float cB[2] = {0.f, 0.f};
        for (int s = 0; s <= 2048; ++s) {
            const int ps = s & 1;
            int fav = aload(fAp);       // early issue; consumed mid-step
            int fcv = aload(fCp);

            if (wave == 0 && s >= 1) {  // funnel h2(s-1)
                u64 hv = *(const u64*)(funB + ((s - 1) & 1) * 256 + lane * 4);
                astore64((u64*)(wsb + H2_OFF + (size_t)((((s - 1) & 3) * NG) + g) * 512) + lane, hv);
            }

            u64 pf = 0;
            const bool dopf = (s + 1 <= 2047);
            if (s < 2048) {
#pragma unroll
                for (int b = 0; b < 2; ++b) {
                    float ac[2][4];
#pragma unroll
                    for (int uu = 0; uu < 2; ++uu)
#pragma unroll
                        for (int gg = 0; gg < 4; ++gg) ac[uu][gg] = 0.f;
#pragma unroll
                    for (int jj = 0; jj < 6; ++jj) {
                        half8v xv = *(const half8v*)(XB + ps * 896 + b * 448 + kg * 56 + jj * 8);
#pragma unroll
                        for (int uu = 0; uu < 2; ++uu)
#pragma unroll
                            for (int gg = 0; gg < 4; ++gg)
#pragma unroll
                                for (int mm = 0; mm < 4; ++mm)
                                    ac[uu][gg] = fdot2f(h2at(wB[uu][gg][jj], mm), h2at(xv, mm), ac[uu][gg]);
                    }
#pragma unroll
                    for (int uu = 0; uu < 2; ++uu)
#pragma unroll
                        for (int gg = 0; gg < 4; ++gg) ac[uu][gg] = bf8f(ac[uu][gg]);
                    if (kg < 2) {
                        const int uu = kg, unit = rg * 2 + uu;
                        const float4 bb = *(const float4*)&biasB[unit * 4];
                        _Float16 hf = lstm_fin(ac[uu][0] + bb.x, ac[uu][1] + bb.y,
                                               ac[uu][2] + bb.z, ac[uu][3] + bb.w, cB[b]);
                        const int k = 256 + unit;
                        XB[((s + 1) & 1) * 896 + b * 448 + (k / 48) * 56 + (k % 48)] = hf;
                        funB[(s & 1) * 256 + b * 128 + unit] = hf;
                    }
                    if (b == 0 && dopf) {   // prefetch h1(s+1) between rounds (latency hides under b1)
                        if (fav < s + 2) fav = spin_ge(fAp, s + 2);
                        if (lane < 16)
                            pf = aload64((const u64*)(wsb + H1_OFF +
                                 (size_t)((((s + 1) & 7) * NG) + g) * 1024) + (wave * 16 + lane));
                    }
                }
                if (dopf && lane < 16) {
                    int hh = (wave * 16 + lane) * 4, b = hh >> 8, off = hh & 255;
                    *(u64*)(XB + ((s + 1) & 1) * 896 + b * 448 + (off / 48) * 56 + (off % 48)) = pf;
                }
            }

            if (wave == 0) {
                asm volatile("s_waitcnt vmcnt(0)" ::: "memory");
                if (lane == 0 && s >= 1) apost(fBp, s);
                if (lane == 0 && s >= 5) { if (fcv < s - 4) spin_ge(fCp, s - 4); }
            }
            __syncthreads();
        }
        return;
    }

    // =================================================================== C
    {
        _Float16* XC = (_Float16*)smem;              // [2][2][248]: h2 0..128 | h3 128..192 | h4 192..224 | h5 224..240
        float* biasC3 = (float*)(smem + 1984);       // [64][4]
        float* biasC4 = (float*)(smem + 3008);       // [32][4]
        float* biasC5 = (float*)(smem + 3520);       // [16][4]
        float* wlC    = (float*)(smem + 3776);       // [16]
        float* blC    = (float*)(smem + 3840);

        // L3: waves 0-3 (KG=8); L4: waves 4-5 (KG=4); L5: wave 6 (KG=2); head+staging: wave 7
        half8v wC3[2][4][3]; half8v wC4[4][3]; half8v wC5[4][3];
        int kg3 = 0, rg3 = 0, kg4 = 0, rg4 = 0, kg5 = 0, rg5 = 0, u5 = 0;

        if (wave < 4) {
            kg3 = tid & 7; rg3 = tid >> 3;           // 0..31
#pragma unroll
            for (int uu = 0; uu < 2; ++uu)
#pragma unroll
                for (int gg = 0; gg < 4; ++gg) {
                    const int row = gg * 64 + rg3 * 2 + uu;
#pragma unroll
                    for (int jj = 0; jj < 3; ++jj) {
                        half8v w;
#pragma unroll
                        for (int e = 0; e < 8; ++e) {
                            const int k = kg3 * 24 + jj * 8 + e;
                            float v = (k < 128) ? w3ih[row * 128 + k] : w3hh[row * 64 + (k - 128)];
                            w[e] = (_Float16)v;
                        }
                        wC3[uu][gg][jj] = w;
                    }
                }
        } else if (wave < 6) {
            const int idx = tid - 256; kg4 = idx & 3; rg4 = idx >> 2;   // 0..31
#pragma unroll
            for (int gg = 0; gg < 4; ++gg) {
                const int row = gg * 32 + rg4;
#pragma unroll
                for (int jj = 0; jj < 3; ++jj) {
                    half8v w;
#pragma unroll
                    for (int e = 0; e < 8; ++e) {
                        const int k = kg4 * 24 + jj * 8 + e;
                        float v = (k < 64) ? w4ih[row * 64 + k] : w4hh[row * 32 + (k - 64)];
                        w[e] = (_Float16)v;
                    }
                    wC4[gg][jj] = w;
                }
            }
        } else if (wave == 6) {
            kg5 = lane & 1; rg5 = lane >> 1; u5 = rg5 & 15;
#pragma unroll
            for (int gg = 0; gg < 4; ++gg) {
                const int row = gg * 16 + u5;
#pragma unroll
                for (int jj = 0; jj < 3; ++jj) {
                    half8v w;
#pragma unroll
                    for (int e = 0; e < 8; ++e) {
                        const int k = kg5 * 24 + jj * 8 + e;
                        float v = (k < 32) ? w5ih[row * 32 + k] : w5hh[row * 16 + (k - 32)];
                        w[e] = (_Float16)v;
                    }
                    wC5[gg][jj] = w;
                }
            }
        }
        for (int i = tid; i < 256; i += 512) { int u = i >> 2, gg = i & 3; biasC3[i] = b3ih[gg*64+u] + b3hh[gg*64+u]; }
        if (tid < 128) { int u = tid >> 2, gg = tid & 3; biasC4[tid] = b4ih[gg*32+u] + b4hh[gg*32+u]; }
        if (tid >= 128 && tid < 192) { int i = tid-128, u = i >> 2, gg = i & 3; biasC5[i] = b5ih[gg*16+u] + b5hh[gg*16+u]; }
        if (tid >= 192 && tid < 208) wlC[tid - 192] = wlin[tid - 192];
        if (tid == 208) *blC = blin[0];
        for (int i = tid; i < 992; i += 512) XC[i] = (_Float16)0.f;
        __syncthreads();
        if (wave == 7) {                 // stage h2(0)
            spin_ge(fBp, 1);
            u64 pf = aload64((const u64*)(wsb + H2_OFF + (size_t)g * 512) + lane);
            int hh = lane * 4;
            *(u64*)(XC + (hh >> 7) * 248 + (hh & 127)) = pf;
        }
        __syncthreads();

        float cC3[2] = {0.f, 0.f}, cC4[2] = {0.f, 0.f}, cC5[2] = {0.f, 0.f};

        for (int s = 0; s <= 2050; ++s) {
            const int ps = s & 1;

            if (wave < 4) {                                   // L3(t=s)
                if (s < 2048) {
#pragma unroll
                    for (int b = 0; b < 2; ++b) {
                        float ac[2][4];
#pragma unroll
                        for (int uu = 0; uu < 2; ++uu)
#pragma unroll
                            for (int gg = 0; gg < 4; ++gg) ac[uu][gg] = 0.f;
#pragma unroll
                        for (int jj = 0; jj < 3; ++jj) {
                            half8v xv = *(const half8v*)(XC + ps * 496 + b * 248 + kg3 * 24 + jj * 8);
#pragma unroll
                            for (int uu = 0; uu < 2; ++uu)
#pragma unroll
                                for (int gg = 0; gg < 4; ++gg)
#pragma unroll
                                    for (int mm = 0; mm < 4; ++mm)
                                        ac[uu][gg] = fdot2f(h2at(wC3[uu][gg][jj], mm), h2at(xv, mm), ac[uu][gg]);
                        }
#pragma unroll
                        for (int uu = 0; uu < 2; ++uu)
#pragma unroll
                            for (int gg = 0; gg < 4; ++gg) ac[uu][gg] = bf8f(ac[uu][gg]);
                        if (kg3 < 2) {
                            const int uu = kg3, unit = rg3 * 2 + uu;
                            const float4 bb = *(const float4*)&biasC3[unit * 4];
                            _Float16 hf = lstm_fin(ac[uu][0]+bb.x, ac[uu][1]+bb.y, ac[uu][2]+bb.z, ac[uu][3]+bb.w, cC3[b]);
                            XC[((s + 1) & 1) * 496 + b * 248 + 128 + unit] = hf;
                        }
                    }
                }
            } else if (wave < 6) {                            // L4(t=s-1)
                if (s >= 1 && s <= 2048) {
#pragma unroll
                    for (int b = 0; b < 2; ++b) {
                        float ac[4] = {0.f, 0.f, 0.f, 0.f};
#pragma unroll
                        for (int jj = 0; jj < 3; ++jj) {
                            half8v xv = *(const half8v*)(XC + ps * 496 + b * 248 + 128 + kg4 * 24 + jj * 8);
#pragma unroll
                            for (int gg = 0; gg < 4; ++gg)
#pragma unroll
                                for (int mm = 0; mm < 4; ++mm)
                                    ac[gg] = fdot2f(h2at(wC4[gg][jj], mm), h2at(xv, mm), ac[gg]);
                        }
#pragma unroll
                        for (int gg = 0; gg < 4; ++gg) ac[gg] = bf4f(ac[gg]);
                        if (kg4 == 0) {
                            const float4 bb = *(const float4*)&biasC4[rg4 * 4];
                            _Float16 hf = lstm_fin(ac[0]+bb.x, ac[1]+bb.y, ac[2]+bb.z, ac[3]+bb.w, cC4[b]);
                            XC[((s + 1) & 1) * 496 + b * 248 + 192 + rg4] = hf;
                        }
                    }
                }
            } else if (wave == 6) {                           // L5(t=s-2)
                if (s >= 2 && s <= 2049) {
#pragma unroll
                    for (int b = 0; b < 2; ++b) {
                        float ac[4] = {0.f, 0.f, 0.f, 0.f};
#pragma unroll
                        for (int jj = 0; jj < 3; ++jj) {
                            half8v xv = *(const half8v*)(XC + ps * 496 + b * 248 + 192 + kg5 * 24 + jj * 8);
#pragma unroll
                            for (int gg = 0; gg < 4; ++gg)
#pragma unroll
                                for (int mm = 0; mm < 4; ++mm)
                                    ac[gg] = fdot2f(h2at(wC5[gg][jj], mm), h2at(xv, mm), ac[gg]);
                        }
#pragma unroll
                        for (int gg = 0; gg < 4; ++gg) ac[gg] = bf2f(ac[gg]);
                        if (kg5 == 0 && rg5 < 16) {
                            const float4 bb = *(const float4*)&biasC5[u5 * 4];
                            _Float16 hf = lstm_fin(ac[0]+bb.x, ac[1]+bb.y, ac[2]+bb.z, ac[3]+bb.w, cC5[b]);
                            XC[((s + 1) & 1) * 496 + b * 248 + 224 + u5] = hf;
                        }
                    }
                }
            } else {                                          // wave 7: head(t=s-3) + h2 staging
                int fbv = aload(fBp);
                const int l = lane;
                if (l < 2 && s >= 3) {
                    float a = *blC;
                    const _Float16* hp = XC + ps * 496 + l * 248 + 224;
                    half8v h0 = *(const half8v*)hp;
                    half8v h1x = *(const half8v*)(hp + 8);
#pragma unroll
                    for (int j = 0; j < 8; ++j) a = fmaf((float)h0[j], wlC[j], a);
#pragma unroll
                    for (int j = 0; j < 8; ++j) a = fmaf((float)h1x[j], wlC[8 + j], a);
                    out[(size_t)(g * 2 + l) * TT + (s - 3)] = a;
                }
                if (s + 1 <= 2047) {                          // prefetch+stage h2(s+1)
                    if (fbv < s + 2) fbv = spin_ge(fBp, s + 2);
                    u64 pf = aload64((const u64*)(wsb + H2_OFF +
                              (size_t)((((s + 1) & 3) * NG) + g) * 512) + l);
                    int hh = l * 4;
                    *(u64*)(XC + ((s + 1) & 1) * 496 + (hh >> 7) * 248 + (hh & 127)) = pf;
                }
                if (l == 0) apost(fCp, s + 1);               // read-receipt for B's ring
            }
            __syncthreads();
        }
        return;
    }
}

extern "C" void kernel_launch(void* const* d_in, const int* in_sizes, int n_in,
                              void* d_out, int out_size, void* d_ws, size_t ws_size,
                              hipStream_t stream) {
    (void)in_sizes; (void)out_size; (void)ws_size;
    const float* p[23];
    for (int i = 0; i < 23 && i < n_in; ++i) p[i] = (const float*)d_in[i];

    prep_v4<<<dim3(64), dim3(512), 0, stream>>>((char*)d_ws, p[2]);

    // 64 groups x {A,B,C} = 192 blocks; VGPR>128 forces 1 block/CU -> all resident.
    lstm_v4<<<dim3(192), dim3(512), 0, stream>>>(
        p[0],
        p[1],  p[2],  p[3],  p[4],
        p[5],  p[6],  p[7],  p[8],
        p[9],  p[10], p[11], p[12],
        p[13], p[14], p[15], p[16],
        p[17], p[18], p[19], p[20],
        p[21], p[22],
        (float*)d_out, (char*)d_ws);
}

// Round 5
// 9114.005 us; speedup vs baseline: 2.0853x; 2.0853x over previous
//
#include <hip/hip_runtime.h>
#include <math.h>

#define TT 2048
#define NSTEP 2053   // 2048 + 4 pipeline fill + 1 head drain

// ---- d_ws layout (bytes) ----
// [0, 786432)    board: u64 [3 slot][32 group][4 batch][256 q]
//                each u64 = { h[2q] u16, h[2q+1] u16, tag u32 = producer_step+1 }
// [786432, +16K) flags: int [32 group][8 member] stride 16 ints (monotone step cnt)
#define FLAGS_BOFF 786432
#define ZERO_F4    50176     // float4 count covering board+flags (802816 B)

// per-wave private LDS x-buffer: 4 batch rows x XW halves
#define XW  392              // 784B row stride: 196 dwords = 4 mod 32 -> 4-bank row skew
#define XPW (4 * XW)
#define LDS_BYTES 90112      // > 80KB forces 1 block/CU; actual use = 8*XPW*2 = 25088B

typedef _Float16 half2v __attribute__((ext_vector_type(2)));
typedef _Float16 half8v __attribute__((ext_vector_type(8)));
typedef unsigned long long u64;

#if defined(__has_builtin)
#if __has_builtin(__builtin_amdgcn_fdot2)
#define HAVE_FDOT2 1
#endif
#endif

__device__ __forceinline__ float fdot2f(half2v a, half2v b, float c) {
#ifdef HAVE_FDOT2
    return __builtin_amdgcn_fdot2(a, b, c, false);
#else
    return c + (float)a.x * (float)b.x + (float)a.y * (float)b.y;
#endif
}
__device__ __forceinline__ half2v h2at(half8v v, int m) {
    half2v r; r.x = v[2 * m]; r.y = v[2 * m + 1]; return r;
}
__device__ __forceinline__ float sigf(float x) { return 1.0f / (1.0f + __expf(-x)); }
__device__ __forceinline__ float tanh_f(float x) {
    float t = __expf(fminf(2.0f * x, 30.0f));
    return (t - 1.0f) / (t + 1.0f);
}

// cross-lane add, xor distance 1/2 via DPP quad_perm (VALU pipe, not LDS)
template<int CTRL, int XM>
__device__ __forceinline__ float xadd(float v) {
#if __has_builtin(__builtin_amdgcn_mov_dpp)
    int t = __builtin_amdgcn_mov_dpp(__builtin_bit_cast(int, v), CTRL, 0xF, 0xF, true);
    return v + __builtin_bit_cast(float, t);
#else
    return v + __shfl_xor(v, XM, 64);
#endif
}
// xor distance 4 via ds_swizzle (1 LDS op, no address VALU)
__device__ __forceinline__ float xadd4(float v) {
#if __has_builtin(__builtin_amdgcn_ds_swizzle)
    int t = __builtin_amdgcn_ds_swizzle(__builtin_bit_cast(int, v), 0x101F);
    return v + __builtin_bit_cast(float, t);
#else
    return v + __shfl_xor(v, 4, 64);
#endif
}

__device__ __forceinline__ int aload(const int* p) {
    return __hip_atomic_load((int*)p, __ATOMIC_RELAXED, __HIP_MEMORY_SCOPE_AGENT);
}
__device__ __forceinline__ u64 aload64(const u64* p) {
    return __hip_atomic_load((u64*)p, __ATOMIC_RELAXED, __HIP_MEMORY_SCOPE_AGENT);
}
__device__ __forceinline__ void astore64(u64* p, u64 v) {
    __hip_atomic_store(p, v, __ATOMIC_RELAXED, __HIP_MEMORY_SCOPE_AGENT);
}

__global__ __launch_bounds__(256)
void prep_zero(float4* ws) {
    int idx = blockIdx.x * 256 + threadIdx.x;
    if (idx < ZERO_F4) ws[idx] = make_float4(0.f, 0.f, 0.f, 0.f);
}

// Spin directly on tagged board data (RAW = single fabric RT), then stage into
// this wave's PRIVATE LDS rows. 16 lanes per batch, CNT u64 per lane, q =
// QSTART + i0 + t*16. Each u64 yields 2 consecutive h -> one u32 LDS write.
template<int CNT, int QSTART>
__device__ __forceinline__ void stage_tag(const u64* __restrict__ bq_r,
                                          _Float16* __restrict__ Xp,
                                          int lane, unsigned want)
{
    const int b = lane >> 4, i0 = lane & 15;
    const u64* src = bq_r + (size_t)b * 256 + QSTART + i0;
    u64 v[CNT];
    while (true) {
        bool ok = true;
#pragma unroll
        for (int t = 0; t < CNT; ++t) v[t] = aload64(src + t * 16);
#pragma unroll
        for (int t = 0; t < CNT; ++t) ok &= ((unsigned)(v[t] >> 32) == want);
        if (__all(ok)) break;
    }
    unsigned* dst = (unsigned*)(Xp + b * XW);
#pragma unroll
    for (int t = 0; t < CNT; ++t) dst[i0 + t * 16] = (unsigned)v[t];
}

// zero+tag store for steps where a staged region has no computed value yet/anymore
template<int RG, int KG, int HBASE>
__device__ __forceinline__ void store_zero6(u64* bq_w, int u, int m, int s) {
    const int kg = u & (KG - 1);
    const int rg = u / KG;
    if (kg < 4 && !(rg & 1))
        astore64(bq_w + (size_t)kg * 256 + ((HBASE + m * RG + rg) >> 1),
                 (u64)(unsigned)(s + 1) << 32);
}

// One layer slice with register-resident weights. Reduce order (xor 1,2,4)
// identical to v2 -> bitwise-identical numerics. Output h is pair-packed via
// __shfl_xor(KG) (rg^1 partner, both active in the kg<4 branch) and stored as
// one tagged 8B unit by the even-rg lane.
template<int RG, int KG, int J, int XLOC, int HBASE, bool ISL1, bool RED8>
__device__ __forceinline__ void layer6(
    const half8v* __restrict__ wfrag, const float* __restrict__ brg,
    const float* __restrict__ w1x, float xt,
    const _Float16* __restrict__ Xp,
    u64* __restrict__ bq_w, float& cpriv, int u, int m, int s)
{
    const int kg = u & (KG - 1);
    const int rg = u / KG;

    float acc[4][4];
#pragma unroll
    for (int i = 0; i < 4; ++i)
#pragma unroll
        for (int j = 0; j < 4; ++j) acc[i][j] = 0.f;

#pragma unroll
    for (int jj = 0; jj < J; ++jj) {
        const int kk = XLOC + kg * 8 + jj * (KG * 8);
        half8v xv[4];
#pragma unroll
        for (int j = 0; j < 4; ++j)
            xv[j] = *(const half8v*)(Xp + j * XW + kk);
#pragma unroll
        for (int i = 0; i < 4; ++i)
#pragma unroll
            for (int j = 0; j < 4; ++j)
#pragma unroll
                for (int mm = 0; mm < 4; ++mm)
                    acc[i][j] = fdot2f(h2at(wfrag[i * J + jj], mm),
                                       h2at(xv[j], mm), acc[i][j]);
    }

#pragma unroll
    for (int i = 0; i < 4; ++i)
#pragma unroll
        for (int j = 0; j < 4; ++j) {
            float a = acc[i][j];
            a = xadd<0xB1, 1>(a);          // quad_perm [1,0,3,2] == xor 1
            a = xadd<0x4E, 2>(a);          // quad_perm [2,3,0,1] == xor 2
            if (RED8) a = xadd4(a);        // ds_swizzle xor 4
            acc[i][j] = a;
        }

    if (kg < 4) {
        const int j = kg;
        float g0 = acc[0][j] + brg[0];
        float g1 = acc[1][j] + brg[1];
        float g2 = acc[2][j] + brg[2];
        float g3 = acc[3][j] + brg[3];
        if (ISL1) {
            g0 = fmaf(w1x[0], xt, g0);
            g1 = fmaf(w1x[1], xt, g1);
            g2 = fmaf(w1x[2], xt, g2);
            g3 = fmaf(w1x[3], xt, g3);
        }
        float ig = sigf(g0), fg = sigf(g1), gg = tanh_f(g2), og = sigf(g3);
        float cn = fmaf(fg, cpriv, ig * gg);
        cpriv = cn;
        float h = og * tanh_f(cn);
        union { _Float16 hf; unsigned short us; } cv;
        cv.hf = (_Float16)h;
        int other = __shfl_xor((int)(unsigned)cv.us, KG, 64);  // rg^1 partner
        if (!(rg & 1)) {
            unsigned dat = (unsigned)cv.us | ((unsigned)other << 16);
            astore64(bq_w + (size_t)j * 256 + ((HBASE + m * RG + rg) >> 1),
                     (u64)dat | ((u64)(unsigned)(s + 1) << 32));
        }
    }
}

__global__ __launch_bounds__(512)
void lstm_v6(const float* __restrict__ inp,
             const float* __restrict__ w1ih, const float* __restrict__ w1hh,
             const float* __restrict__ b1ih, const float* __restrict__ b1hh,
             const float* __restrict__ w2ih, const float* __restrict__ w2hh,
             const float* __restrict__ b2ih, const float* __restrict__ b2hh,
             const float* __restrict__ w3ih, const float* __restrict__ w3hh,
             const float* __restrict__ b3ih, const float* __restrict__ b3hh,
             const float* __restrict__ w4ih, const float* __restrict__ w4hh,
             const float* __restrict__ b4ih, const float* __restrict__ b4hh,
             const float* __restrict__ w5ih, const float* __restrict__ w5hh,
             const float* __restrict__ b5ih, const float* __restrict__ b5hh,
             const float* __restrict__ wlin, const float* __restrict__ blin,
             float* __restrict__ out, char* __restrict__ wsb)
{
    extern __shared__ __align__(16) _Float16 smem[];
    const int tid  = threadIdx.x;
    const int lane = tid & 63;
    const int wave = tid >> 6;
    const int g = blockIdx.x & 31;     // group (members share mod-8 class)
    const int m = blockIdx.x >> 5;     // member 0..7
    _Float16* Xp = smem + wave * XPW;  // this wave's private x buffer

    u64* bu    = (u64*)wsb;
    int* flags = (int*)(wsb + FLAGS_BOFF);

    // ---- register-resident state (loaded once; statically indexed throughout) ----
    half8v wfrag[24];                  // max live: L2 = 4 gates * J=6
    float brg[4]  = {0.f, 0.f, 0.f, 0.f};
    float w1x[4]  = {0.f, 0.f, 0.f, 0.f};
    float wl[16];
    float bl = 0.f;
    float cpriv = 0.f;

    if (wave < 4) {                    // L1: RG=32 KG=8 J=4, k = h1(256)
        const int kg = tid & 7, rg = tid >> 3;
#pragma unroll
        for (int i = 0; i < 4; ++i) {
            const int grow = i * 256 + m * 32 + rg;
#pragma unroll
            for (int jj = 0; jj < 4; ++jj) {
                const int k0 = kg * 8 + jj * 64;
                half8v w;
#pragma unroll
                for (int e = 0; e < 8; ++e)
                    w[e] = (_Float16)w1hh[grow * 256 + k0 + e];
                wfrag[i * 4 + jj] = w;
            }
            brg[i] = b1ih[grow] + b1hh[grow];
            w1x[i] = w1ih[grow];
        }
    } else if (wave < 6) {             // L2: RG=16 KG=8 J=6, k = h1(256)|h2(128)
        const int u = tid - 256;
        const int kg = u & 7, rg = u >> 3;
#pragma unroll
        for (int i = 0; i < 4; ++i) {
            const int grow = i * 128 + m * 16 + rg;
#pragma unroll
            for (int jj = 0; jj < 6; ++jj) {
                const int k0 = kg * 8 + jj * 64;
                half8v w;
#pragma unroll
                for (int e = 0; e < 8; ++e) {
                    const int k = k0 + e;
                    float v = (k < 256) ? w2ih[grow * 256 + k]
                                        : w2hh[grow * 128 + (k - 256)];
                    w[e] = (_Float16)v;
                }
                wfrag[i * 6 + jj] = w;
            }
            brg[i] = b2ih[grow] + b2hh[grow];
        }
    } else if (wave == 6) {            // L3: RG=8 KG=8 J=3, k = h2(128)|h3(64)
        const int u = tid - 384;
        const int kg = u & 7, rg = u >> 3;
#pragma unroll
        for (int i = 0; i < 4; ++i) {
            const int grow = i * 64 + m * 8 + rg;
#pragma unroll
            for (int jj = 0; jj < 3; ++jj) {
                const int k0 = kg * 8 + jj * 64;
                half8v w;
#pragma unroll
                for (int e = 0; e < 8; ++e) {
                    const int k = k0 + e;
                    float v = (k < 128) ? w3ih[grow * 128 + k]
                                        : w3hh[grow * 64 + (k - 128)];
                    w[e] = (_Float16)v;
                }
                wfrag[i * 3 + jj] = w;
            }
            brg[i] = b3ih[grow] + b3hh[grow];
        }
    } else {                           // wave 7: L4 (16 lanes) + L5 (8) + out (4) + pads (32)
        const int u = tid - 448;
        if (u < 16) {                  // L4: RG=4 KG=4 J=3, k = h3(64)|h4(32)
            const int kg = u & 3, rg = u >> 2;
#pragma unroll
            for (int i = 0; i < 4; ++i) {
                const int grow = i * 32 + m * 4 + rg;
#pragma unroll
                for (int jj = 0; jj < 3; ++jj) {
                    const int k0 = kg * 8 + jj * 32;
                    half8v w;
#pragma unroll
                    for (int e = 0; e < 8; ++e) {
                        const int k = k0 + e;
                        float v = (k < 64) ? w4ih[grow * 64 + k]
                                           : w4hh[grow * 32 + (k - 64)];
                        w[e] = (_Float16)v;
                    }
                    wfrag[i * 3 + jj] = w;
                }
                brg[i] = b4ih[grow] + b4hh[grow];
            }
        } else if (u < 24) {           // L5: RG=2 KG=4 J=2, k = h4(32)|h5(16)|pad
            const int uu = u - 16, kg = uu & 3, rg = uu >> 2;
#pragma unroll
            for (int i = 0; i < 4; ++i) {
                const int grow = i * 16 + m * 2 + rg;
#pragma unroll
                for (int jj = 0; jj < 2; ++jj) {
                    const int k0 = kg * 8 + jj * 32;
                    half8v w;
#pragma unroll
                    for (int e = 0; e < 8; ++e) {
                        const int k = k0 + e;
                        float v = (k < 32) ? w5ih[grow * 32 + k]
                                : (k < 48 ? w5hh[grow * 16 + (k - 32)] : 0.f);
                        w[e] = (_Float16)v;
                    }
                    wfrag[i * 2 + jj] = w;
                }
                brg[i] = b5ih[grow] + b5hh[grow];
            }
        } else if (u < 28) {           // out head
#pragma unroll
            for (int j = 0; j < 16; ++j) wl[j] = wlin[j];
            bl = blin[0];
        }
    }

    const int* fp = flags + (g * 8 + (lane & 7)) * 16;
    int* myflag   = flags + (g * 8 + m) * 16;

    int fc = 0;            // cached lower bound on min peer flag (pre-issued)
    int sw = 0, sr = 2;    // write slot = s%3, read slot = (s-1)%3

#define WARCHK(SREQ)                                                     \
    do { if (!__all(fc >= (SREQ))) {                                     \
             do { fc = aload(fp); } while (!__all(fc >= (SREQ)));        \
         } } while (0)

    for (int s = 0; s < NSTEP; ++s) {
        const u64* bq_r = bu + (size_t)(sr * 32 + g) * 1024;
        u64* bq_w       = bu + (size_t)(sw * 32 + g) * 1024;
        // WAR (3-slot ring): before overwriting slot s%3 (last written s-3,
        // read at s-2, readers post flag s-1 after it) need flags >= s-1.
        const int wreq = s - 1;

        if (wave < 4) {                                     // L1
            if (s < 2048) {
                float xt = inp[(size_t)(g * 4 + (lane & 3)) * TT + s];
                stage_tag<8, 0>(bq_r, Xp, lane, (unsigned)s);    // h1
                WARCHK(wreq);
                layer6<32, 8, 4, 0, 0, true, true>(
                    wfrag, brg, w1x, xt, Xp, bq_w, cpriv, tid, m, s);
            }
        } else if (wave < 6) {                              // L2
            if (s >= 1 && s <= 2048) {
                stage_tag<12, 0>(bq_r, Xp, lane, (unsigned)s);   // h1|h2
                WARCHK(wreq);
                layer6<16, 8, 6, 0, 256, false, true>(
                    wfrag, brg, w1x, 0.f, Xp, bq_w, cpriv, tid - 256, m, s);
            } else if (s == 0) {
                WARCHK(wreq);
                store_zero6<16, 8, 256>(bq_w, tid - 256, m, s);
            }
        } else if (wave == 6) {                             // L3
            if (s >= 2 && s <= 2049) {
                stage_tag<6, 128>(bq_r, Xp, lane, (unsigned)s);  // h2|h3
                WARCHK(wreq);
                layer6<8, 8, 3, 0, 384, false, true>(
                    wfrag, brg, w1x, 0.f, Xp, bq_w, cpriv, tid - 384, m, s);
            } else if (s == 1 || s == 2050 || s == 2051) {
                WARCHK(wreq);
                store_zero6<8, 8, 384>(bq_w, tid - 384, m, s);
            }
        } else {                                            // wave 7
            const int u = tid - 448;
            if (s >= 3 && s <= 2052)
                stage_tag<4, 192>(bq_r, Xp, lane, (unsigned)s);  // h3|h4|h5|pad
            if (s <= 2051) WARCHK(wreq);                    // all w7 stores end at 2051
            if (u < 16) {
                if (s >= 3 && s <= 2050)
                    layer6<4, 4, 3, 0, 448, false, false>(
                        wfrag, brg, w1x, 0.f, Xp, bq_w, cpriv, u, m, s);
                else if (s == 2 || s == 2051)
                    store_zero6<4, 4, 448>(bq_w, u, m, s);
            } else if (u < 24) {
                if (s >= 4 && s <= 2051)
                    layer6<2, 4, 2, 64, 480, false, false>(
                        wfrag, brg, w1x, 0.f, Xp, bq_w, cpriv, u - 16, m, s);
                else if (s == 2 || s == 3)
                    store_zero6<2, 4, 480>(bq_w, u - 16, m, s);
            } else if (u < 28) {
                if (m == 0 && s >= 5) {
                    const int b = u - 24;
                    float a = bl;
#pragma unroll
                    for (int j = 0; j < 16; ++j)
                        a = fmaf((float)Xp[b * XW + 96 + j], wl[j], a);
                    out[(size_t)(g * 4 + b) * TT + (s - 5)] = a;
                }
            } else if (u < 60) {                            // pad tags h496..511
                if (s >= 2 && s <= 2051) {
                    const int idx = u - 28;                 // 32 units: [b][q-248]
                    astore64(bq_w + (size_t)(idx >> 3) * 256 + 248 + (idx & 7),
                             (u64)(unsigned)(s + 1) << 32);
                }
            }
        }

        // ---- one barrier per step: all waves' stage reads done -> post member
        // flag (WAR receipt only; RAW is carried by the tags). Then pre-issue
        // next step's WAR flag sample (latency hides under next stage+compute).
        __syncthreads();
        if (tid == 0)
            __hip_atomic_store(myflag, s + 1, __ATOMIC_RELAXED,
                               __HIP_MEMORY_SCOPE_AGENT);
        fc = aload(fp);
        sr = sw;
        sw = (sw == 2) ? 0 : sw + 1;
    }
#undef WARCHK
}

extern "C" void kernel_launch(void* const* d_in, const int* in_sizes, int n_in,
                              void* d_out, int out_size, void* d_ws, size_t ws_size,
                              hipStream_t stream) {
    const float* p[23];
    for (int i = 0; i < 23 && i < n_in; ++i) p[i] = (const float*)d_in[i];

    (void)hipFuncSetAttribute((const void*)lstm_v6,
                              hipFuncAttributeMaxDynamicSharedMemorySize,
                              LDS_BYTES);

    prep_zero<<<dim3((ZERO_F4 + 255) / 256), dim3(256), 0, stream>>>((float4*)d_ws);

    // grid 256 = CU count; >80KB dynamic LDS forces 1 block/CU -> all blocks
    // co-resident (required for the tag/flag protocol).
    lstm_v6<<<dim3(256), dim3(512), LDS_BYTES, stream>>>(
        p[0],
        p[1],  p[2],  p[3],  p[4],
        p[5],  p[6],  p[7],  p[8],
        p[9],  p[10], p[11], p[12],
        p[13], p[14], p[15], p[16],
        p[17], p[18], p[19], p[20],
        p[21], p[22],
        (float*)d_out, (char*)d_ws);
}

// Round 6
// 6278.780 us; speedup vs baseline: 3.0269x; 1.4516x over previous
//
#include <hip/hip_runtime.h>
#include <math.h>

#define TT 2048
#define NSLOT 6

// ---- d_ws layout (bytes) ----
// [0, 786432)    board: u64 [6 slot][128 g][128 q], q = {h[2q],h[2q+1], tag32}
// [786432, +8K)  fB: int per group, stride 64 B (M1 receipt: consumed h1 idx + 1)
#define FB_OFF  786432
#define ZERO_F4 49664          // (786432 + 8192) / 16

// ---- dynamic LDS (halves) ----
// M0: lw1 [512 lane][2 row][72]   (= 73728 h) | X0 [2][256] @ 73728
// M1: lw2 [512][96] | lw3 [512][48] @ 49152   | X1 [2][512] @ 73728
#define M0_X   73728
#define M1_LW3 49152
#define M1_X   73728
#define LDS_BYTES 149504       // 74752 halves (M1 is larger); forces 1 block/CU

typedef _Float16 half2v __attribute__((ext_vector_type(2)));
typedef _Float16 half4v __attribute__((ext_vector_type(4)));
typedef _Float16 half8v __attribute__((ext_vector_type(8)));
typedef unsigned long long u64;
typedef unsigned int u32;

#if defined(__has_builtin)
#if __has_builtin(__builtin_amdgcn_fdot2)
#define HAVE_FDOT2 1
#endif
#endif

__device__ __forceinline__ float fdot2f(half2v a, half2v b, float c) {
#ifdef HAVE_FDOT2
    return __builtin_amdgcn_fdot2(a, b, c, false);
#else
    return c + (float)a.x * (float)b.x + (float)a.y * (float)b.y;
#endif
}
__device__ __forceinline__ half2v h2at(half8v v, int m) {
    half2v r; r.x = v[2 * m]; r.y = v[2 * m + 1]; return r;
}
__device__ __forceinline__ float dot8(half8v w, half8v x, float a) {
#pragma unroll
    for (int m = 0; m < 4; ++m) a = fdot2f(h2at(w, m), h2at(x, m), a);
    return a;
}
__device__ __forceinline__ half2v h2lo(half4v v) { half2v r; r.x = v[0]; r.y = v[1]; return r; }
__device__ __forceinline__ half2v h2hi(half4v v) { half2v r; r.x = v[2]; r.y = v[3]; return r; }

__device__ __forceinline__ float sigf(float x) { return 1.0f / (1.0f + __expf(-x)); }
__device__ __forceinline__ float tanh_f(float x) {
    float t = __expf(fminf(2.0f * x, 30.0f));
    return (t - 1.0f) / (t + 1.0f);
}
template<int CTRL, int XM>
__device__ __forceinline__ float xadd(float v) {
#if __has_builtin(__builtin_amdgcn_mov_dpp)
    int t = __builtin_amdgcn_mov_dpp(__builtin_bit_cast(int, v), CTRL, 0xF, 0xF, true);
    return v + __builtin_bit_cast(float, t);
#else
    return v + __shfl_xor(v, XM, 64);
#endif
}
__device__ __forceinline__ float xadd4(float v) {
#if __has_builtin(__builtin_amdgcn_ds_swizzle)
    int t = __builtin_amdgcn_ds_swizzle(__builtin_bit_cast(int, v), 0x101F);
    return v + __builtin_bit_cast(float, t);
#else
    return v + __shfl_xor(v, 4, 64);
#endif
}
__device__ __forceinline__ _Float16 lstm_fin(float g0, float g1, float g2, float g3, float& c) {
    float ig = sigf(g0), fg = sigf(g1), gg = tanh_f(g2), og = sigf(g3);
    float cn = fmaf(fg, c, ig * gg); c = cn;
    return (_Float16)(og * tanh_f(cn));
}
__device__ __forceinline__ int aload(const int* p) {
    return __hip_atomic_load((int*)p, __ATOMIC_RELAXED, __HIP_MEMORY_SCOPE_AGENT);
}
__device__ __forceinline__ void apost(int* p, int v) {
    __hip_atomic_store(p, v, __ATOMIC_RELAXED, __HIP_MEMORY_SCOPE_AGENT);
}
__device__ __forceinline__ u64 aload64(const u64* p) {
    return __hip_atomic_load((u64*)p, __ATOMIC_RELAXED, __HIP_MEMORY_SCOPE_AGENT);
}
__device__ __forceinline__ void astore64(u64* p, u64 v) {
    __hip_atomic_store(p, v, __ATOMIC_RELAXED, __HIP_MEMORY_SCOPE_AGENT);
}

__global__ __launch_bounds__(256)
void prep_zero(float4* ws) {
    int idx = blockIdx.x * 256 + threadIdx.x;
    if (idx < ZERO_F4) ws[idx] = make_float4(0.f, 0.f, 0.f, 0.f);
}

__global__ __launch_bounds__(512, 1)
void lstm_v7(const float* __restrict__ inp,
             const float* __restrict__ w1ih, const float* __restrict__ w1hh,
             const float* __restrict__ b1ih, const float* __restrict__ b1hh,
             const float* __restrict__ w2ih, const float* __restrict__ w2hh,
             const float* __restrict__ b2ih, const float* __restrict__ b2hh,
             const float* __restrict__ w3ih, const float* __restrict__ w3hh,
             const float* __restrict__ b3ih, const float* __restrict__ b3hh,
             const float* __restrict__ w4ih, const float* __restrict__ w4hh,
             const float* __restrict__ b4ih, const float* __restrict__ b4hh,
             const float* __restrict__ w5ih, const float* __restrict__ w5hh,
             const float* __restrict__ b5ih, const float* __restrict__ b5hh,
             const float* __restrict__ wlin, const float* __restrict__ blin,
             float* __restrict__ out, char* __restrict__ wsb)
{
    extern __shared__ __align__(16) _Float16 smem[];
    const int tid  = threadIdx.x;
    const int lane = tid & 63;
    const int wave = tid >> 6;
    const int g = blockIdx.x >> 1;          // group = batch element (0..127)
    u64* board = (u64*)wsb;
    int* fBp = (int*)(wsb + FB_OFF) + g * 16;

    if ((blockIdx.x & 1) == 0) {
        // ========================= M0 : layer 1 =========================
        _Float16* lw = smem;                 // [512][2][72]
        _Float16* X0 = smem + M0_X;          // [2][256] h1 state, double-buffered
        const int kg = tid & 3, slot = tid >> 2;   // KG=4, 128 slots x 2 units
        const int du = kg & 1;

        half8v w[6][8];                      // rows: gate(0..2) x unit(0,1); 192 VGPR
#pragma unroll
        for (int r = 0; r < 6; ++r) {
            const int grow = (r >> 1) * 256 + slot * 2 + (r & 1);
#pragma unroll
            for (int j = 0; j < 8; ++j) {
                half8v t;
#pragma unroll
                for (int e = 0; e < 8; ++e)
                    t[e] = (_Float16)w1hh[grow * 256 + kg * 64 + j * 8 + e];
                w[r][j] = t;
            }
        }
        for (int rr = 0; rr < 2; ++rr) {     // gate-3 rows (both units) -> LDS
            const int grow = 3 * 256 + slot * 2 + rr;
            for (int e = 0; e < 64; ++e)
                lw[(tid * 2 + rr) * 72 + e] =
                    (_Float16)w1hh[grow * 256 + kg * 64 + e];
        }
        float b4[4], wx4[4];
#pragma unroll
        for (int gg = 0; gg < 4; ++gg) {
            const int gr = gg * 256 + slot * 2 + du;
            b4[gg] = b1ih[gr] + b1hh[gr];
            wx4[gg] = w1ih[gr];
        }
        for (int i = tid; i < 512; i += 512) X0[i] = (_Float16)0.f;
        __syncthreads();

        float c1 = 0.f;
        float xcur = inp[(size_t)g * TT];
        int fc = 0, fnew = 0;
        const _Float16* lwp0 = lw + (tid * 2) * 72;
        const _Float16* lwp1 = lw + (tid * 2 + 1) * 72;

        for (int s = 0; s <= 2048; ++s) {
            const int ph = s & 1, nph = ph ^ 1;

            // wave0: pack h1(s-1) -> board (tagged; fire-and-forget)
            if (wave == 0 && s >= 1) {
                if (s >= 7 && fc < s - 5) {          // 6-slot WAR back-pressure
                    do { fc = aload(fBp); } while (fc < s - 5);
                }
                u64 hv = *(const u64*)(X0 + ph * 256 + lane * 4);
                u64* dst = board + ((size_t)((s - 1) % NSLOT) * 128 + g) * 128 + lane * 2;
                const u64 tg = (u64)(u32)s << 32;    // tag for h1(s-1) = s
                astore64(dst,     (hv & 0xffffffffull) | tg);
                astore64(dst + 1, (hv >> 32)           | tg);
                fnew = aload(fBp);                   // pre-issued; used next step
            }

            if (s < 2048) {
                const float xt = xcur;
                if (s + 1 < 2048) xcur = inp[(size_t)g * TT + s + 1];
                float acc[8];
#pragma unroll
                for (int r = 0; r < 8; ++r) acc[r] = 0.f;
#pragma unroll
                for (int c = 0; c < 8; ++c) {        // 8-half chunks of x = h1(s-1)
                    const half8v xa = *(const half8v*)(X0 + ph * 256 + kg * 64 + c * 8);
#pragma unroll
                    for (int r = 0; r < 6; ++r)
                        acc[r] = dot8(w[r][c], xa, acc[r]);
                    const half8v la = *(const half8v*)(lwp0 + c * 8);
                    acc[6] = dot8(la, xa, acc[6]);
                    const half8v ma = *(const half8v*)(lwp1 + c * 8);
                    acc[7] = dot8(ma, xa, acc[7]);
                }
#pragma unroll
                for (int r = 0; r < 8; ++r) {
                    float a = acc[r];
                    a = xadd<0xB1, 1>(a);            // xor1 (dpp)
                    a = xadd<0x4E, 2>(a);            // xor2 (dpp)
                    acc[r] = a;
                }
                if (kg < 2) {                        // one lane per unit
                    float g0 = fmaf(wx4[0], xt, acc[0 + kg] + b4[0]);
                    float g1 = fmaf(wx4[1], xt, acc[2 + kg] + b4[1]);
                    float g2 = fmaf(wx4[2], xt, acc[4 + kg] + b4[2]);
                    float g3 = fmaf(wx4[3], xt, acc[6 + kg] + b4[3]);
                    X0[nph * 256 + slot * 2 + kg] = lstm_fin(g0, g1, g2, g3, c1);
                }
            }
            __syncthreads();
            if (fnew > fc) fc = fnew;
        }
        return;
    }

    // ========================= M1 : layers 2..5 + head =========================
    _Float16* lw2 = smem;                    // [512][96] (L2 gate-3 row)
    _Float16* lw3 = smem + M1_LW3;           // [512][48] (L3 2nd row)
    _Float16* X1  = smem + M1_X;             // [2][512]: h1 0..256|h2 256..384|h3 384..448|h4 448..480|h5 480..496
    const int kg = tid & 3;
    const int unit2 = tid >> 2;              // 0..127
    const int unit3 = tid >> 3;              // 0..63
    const int sub = (tid >> 2) & 1;

    half8v w2[3][12];                        // L2 gates 0..2; 144 VGPR
#pragma unroll
    for (int r = 0; r < 3; ++r) {
        const int grow = r * 128 + unit2;
#pragma unroll
        for (int j = 0; j < 12; ++j) {
            half8v t;
#pragma unroll
            for (int e = 0; e < 8; ++e) {
                const int k = kg * 96 + j * 8 + e;
                t[e] = (_Float16)((k < 256) ? w2ih[grow * 256 + k]
                                            : w2hh[grow * 128 + (k - 256)]);
            }
            w2[r][j] = t;
        }
    }
    {
        const int grow = 3 * 128 + unit2;    // L2 gate-3 -> LDS
        for (int e = 0; e < 96; ++e) {
            const int k = kg * 96 + e;
            lw2[tid * 96 + e] = (_Float16)((k < 256) ? w2ih[grow * 256 + k]
                                                     : w2hh[grow * 128 + (k - 256)]);
        }
    }
    half8v w3[6];                            // L3 row A (gate sub*2); 24 VGPR
    {
        const int grow = (sub * 2) * 64 + unit3;
#pragma unroll
        for (int j = 0; j < 6; ++j) {
            half8v t;
            for (int e = 0; e < 8; ++e) {
                const int k = kg * 48 + j * 8 + e;
                t[e] = (_Float16)((k < 128) ? w3ih[grow * 128 + k]
                                            : w3hh[grow * 64 + (k - 128)]);
            }
            w3[j] = t;
        }
        const int grow1 = (sub * 2 + 1) * 64 + unit3;   // row B -> LDS
        for (int e = 0; e < 48; ++e) {
            const int k = kg * 48 + e;
            lw3[tid * 48 + e] = (_Float16)((k < 128) ? w3ih[grow1 * 128 + k]
                                                     : w3hh[grow1 * 64 + (k - 128)]);
        }
    }
    half2v wt[4][6];                         // L4 (lanes 128..383) / L5 (384..447)
    float bt[4] = {0.f, 0.f, 0.f, 0.f};
    if (tid >= 128 && tid < 384) {
        const int l = tid - 128, unit4 = l >> 3, kg8 = l & 7;
#pragma unroll
        for (int gg = 0; gg < 4; ++gg) {
            const int grow = gg * 32 + unit4;
#pragma unroll
            for (int m = 0; m < 6; ++m) {
                half2v t;
                for (int e = 0; e < 2; ++e) {
                    const int k = kg8 * 12 + m * 2 + e;
                    t[e] = (_Float16)((k < 64) ? w4ih[grow * 64 + k]
                                               : w4hh[grow * 32 + (k - 64)]);
                }
                wt[gg][m] = t;
            }
            bt[gg] = b4ih[grow] + b4hh[grow];
        }
    } else if (tid >= 384 && tid < 448) {
        const int l = tid - 384, unit5 = l >> 2, kg5 = l & 3;
#pragma unroll
        for (int gg = 0; gg < 4; ++gg) {
            const int grow = gg * 16 + unit5;
#pragma unroll
            for (int m = 0; m < 6; ++m) {
                half2v t;
                for (int e = 0; e < 2; ++e) {
                    const int k = kg5 * 12 + m * 2 + e;
                    t[e] = (_Float16)((k < 32) ? w5ih[grow * 32 + k]
                                               : w5hh[grow * 16 + (k - 32)]);
                }
                wt[gg][m] = t;
            }
            bt[gg] = b5ih[grow] + b5hh[grow];
        }
    }
    float b2v[4], b3v[4];
#pragma unroll
    for (int gg = 0; gg < 4; ++gg) {
        b2v[gg] = b2ih[gg * 128 + unit2] + b2hh[gg * 128 + unit2];
        b3v[gg] = b3ih[gg * 64 + unit3] + b3hh[gg * 64 + unit3];
    }
    float wlj = 0.f, blv = 0.f;
    if (tid >= 448 && tid < 464) { wlj = wlin[tid - 448]; blv = blin[0]; }

    for (int i = tid; i < 1024; i += 512) X1[i] = (_Float16)0.f;
    __syncthreads();
    if (wave == 7) {                         // prologue: stage h1(0) (tag 1)
        const u64* src = board + (size_t)g * 128 + 2 * lane;
        u64 a, b;
        do { a = aload64(src); b = aload64(src + 1); }
        while (!__all(((u32)(a >> 32) == 1u) && ((u32)(b >> 32) == 1u)));
        *(u64*)(X1 + 4 * lane) = (u64)(u32)a | ((u64)(u32)b << 32);
    }
    __syncthreads();

    float c2 = 0.f, c3 = 0.f, ct = 0.f;
    for (int t = 0; t <= 2051; ++t) {
        const int ph = t & 1, nph = ph ^ 1;
        u64 pa = 0, pb = 0;
        const bool dopf = (t + 1 <= 2047);
        const u64* psrc = board + ((size_t)((t + 1) % NSLOT) * 128 + g) * 128 + 2 * lane;
        if (wave == 7 && dopf) { pa = aload64(psrc); pb = aload64(psrc + 1); }  // prefetch h1(t+1)

        // ---- L2 computes h2(t) ----
        if (t <= 2047) {
            float a0 = 0.f, a1 = 0.f, a2 = 0.f, a3 = 0.f;
#pragma unroll
            for (int c = 0; c < 12; ++c) {
                const half8v xa = *(const half8v*)(X1 + ph * 512 + kg * 96 + c * 8);
                a0 = dot8(w2[0][c], xa, a0);
                a1 = dot8(w2[1][c], xa, a1);
                a2 = dot8(w2[2][c], xa, a2);
                const half8v la = *(const half8v*)(lw2 + tid * 96 + c * 8);
                a3 = dot8(la, xa, a3);
            }
            a0 = xadd<0xB1,1>(a0); a0 = xadd<0x4E,2>(a0);
            a1 = xadd<0xB1,1>(a1); a1 = xadd<0x4E,2>(a1);
            a2 = xadd<0xB1,1>(a2); a2 = xadd<0x4E,2>(a2);
            a3 = xadd<0xB1,1>(a3); a3 = xadd<0x4E,2>(a3);
            if (kg == 0)
                X1[nph * 512 + 256 + unit2] =
                    lstm_fin(a0 + b2v[0], a1 + b2v[1], a2 + b2v[2], a3 + b2v[3], c2);
        }
        // ---- L3 computes h3(t-1) ----
        if (t >= 1 && t <= 2048) {
            float sA = 0.f, sB = 0.f;
#pragma unroll
            for (int c = 0; c < 6; ++c) {
                const half8v xa = *(const half8v*)(X1 + ph * 512 + 256 + kg * 48 + c * 8);
                sA = dot8(w3[c], xa, sA);
                const half8v la = *(const half8v*)(lw3 + tid * 48 + c * 8);
                sB = dot8(la, xa, sB);
            }
            sA = xadd<0xB1,1>(sA); sA = xadd<0x4E,2>(sA);
            sB = xadd<0xB1,1>(sB); sB = xadd<0x4E,2>(sB);
            const float sA2 = __shfl_xor(sA, 4, 64);
            const float sB2 = __shfl_xor(sB, 4, 64);
            if (kg == 0 && sub == 0)
                X1[nph * 512 + 384 + unit3] =
                    lstm_fin(sA + b3v[0], sB + b3v[1], sA2 + b3v[2], sB2 + b3v[3], c3);
        }
        // ---- L4 computes h4(t-2): lanes 128..383 (KG=8) ----
        if (tid >= 128 && tid < 384 && t >= 2 && t <= 2049) {
            const int l = tid - 128, kg8 = l & 7, unit4 = l >> 3;
            const _Float16* xp = X1 + ph * 512 + 384 + kg8 * 12;
            const half4v x0 = *(const half4v*)(xp);
            const half4v x1 = *(const half4v*)(xp + 4);
            const half4v x2 = *(const half4v*)(xp + 8);
            float a[4] = {0.f, 0.f, 0.f, 0.f};
#pragma unroll
            for (int gg = 0; gg < 4; ++gg) {
                a[gg] = fdot2f(wt[gg][0], h2lo(x0), a[gg]);
                a[gg] = fdot2f(wt[gg][1], h2hi(x0), a[gg]);
                a[gg] = fdot2f(wt[gg][2], h2lo(x1), a[gg]);
                a[gg] = fdot2f(wt[gg][3], h2hi(x1), a[gg]);
                a[gg] = fdot2f(wt[gg][4], h2lo(x2), a[gg]);
                a[gg] = fdot2f(wt[gg][5], h2hi(x2), a[gg]);
            }
#pragma unroll
            for (int gg = 0; gg < 4; ++gg) {
                float v = a[gg];
                v = xadd<0xB1,1>(v); v = xadd<0x4E,2>(v); v = xadd4(v);
                a[gg] = v;
            }
            if (kg8 == 0)
                X1[nph * 512 + 448 + unit4] =
                    lstm_fin(a[0] + bt[0], a[1] + bt[1], a[2] + bt[2], a[3] + bt[3], ct);
        }
        // ---- L5 computes h5(t-3): lanes 384..447 (KG=4) ----
        if (tid >= 384 && tid < 448 && t >= 3 && t <= 2050) {
            const int l = tid - 384, kg5 = l & 3, unit5 = l >> 2;
            const _Float16* xp = X1 + ph * 512 + 448 + kg5 * 12;
            const half4v x0 = *(const half4v*)(xp);
            const half4v x1 = *(const half4v*)(xp + 4);
            const half4v x2 = *(const half4v*)(xp + 8);
            float a[4] = {0.f, 0.f, 0.f, 0.f};
#pragma unroll
            for (int gg = 0; gg < 4; ++gg) {
                a[gg] = fdot2f(wt[gg][0], h2lo(x0), a[gg]);
                a[gg] = fdot2f(wt[gg][1], h2hi(x0), a[gg]);
                a[gg] = fdot2f(wt[gg][2], h2lo(x1), a[gg]);
                a[gg] = fdot2f(wt[gg][3], h2hi(x1), a[gg]);
                a[gg] = fdot2f(wt[gg][4], h2lo(x2), a[gg]);
                a[gg] = fdot2f(wt[gg][5], h2hi(x2), a[gg]);
            }
#pragma unroll
            for (int gg = 0; gg < 4; ++gg) {
                float v = a[gg];
                v = xadd<0xB1,1>(v); v = xadd<0x4E,2>(v);
                a[gg] = v;
            }
            if (kg5 == 0)
                X1[nph * 512 + 480 + unit5] =
                    lstm_fin(a[0] + bt[0], a[1] + bt[1], a[2] + bt[2], a[3] + bt[3], ct);
        }
        // ---- head outputs y(t-4) (wave7, 16 lanes) ----
        if (wave == 7 && lane < 16 && t >= 4) {
            float p = wlj * (float)X1[ph * 512 + 480 + lane];
            p += __shfl_xor(p, 1, 64); p += __shfl_xor(p, 2, 64);
            p += __shfl_xor(p, 4, 64); p += __shfl_xor(p, 8, 64);
            if (lane == 0) out[(size_t)g * TT + (t - 4)] = p + blv;
        }
        // ---- stage commit: h1(t+1) -> X1[next phase]; post receipt ----
        if (wave == 7 && dopf) {
            const u32 want = (u32)(t + 2);
            while (!__all(((u32)(pa >> 32) == want) && ((u32)(pb >> 32) == want))) {
                pa = aload64(psrc); pb = aload64(psrc + 1);
            }
            *(u64*)(X1 + nph * 512 + 4 * lane) = (u64)(u32)pa | ((u64)(u32)pb << 32);
            if (lane == 0) apost(fBp, t + 2);
        }
        __syncthreads();
    }
}

extern "C" void kernel_launch(void* const* d_in, const int* in_sizes, int n_in,
                              void* d_out, int out_size, void* d_ws, size_t ws_size,
                              hipStream_t stream) {
    const float* p[23];
    for (int i = 0; i < 23 && i < n_in; ++i) p[i] = (const float*)d_in[i];

    (void)hipFuncSetAttribute((const void*)lstm_v7,
                              hipFuncAttributeMaxDynamicSharedMemorySize,
                              LDS_BYTES);

    prep_zero<<<dim3((ZERO_F4 + 255) / 256), dim3(256), 0, stream>>>((float4*)d_ws);

    // grid 256 = CU count; ~146 KB LDS -> 1 block/CU -> all M0/M1 pairs co-resident.
    lstm_v7<<<dim3(256), dim3(512), LDS_BYTES, stream>>>(
        p[0],
        p[1],  p[2],  p[3],  p[4],
        p[5],  p[6],  p[7],  p[8],
        p[9],  p[10], p[11], p[12],
        p[13], p[14], p[15], p[16],
        p[17], p[18], p[19], p[20],
        p[21], p[22],
        (float*)d_out, (char*)d_ws);
}